// Round 6
// baseline (474.100 us; speedup 1.0000x reference)
//
#include <hip/hip_runtime.h>

typedef _Float16 half8 __attribute__((ext_vector_type(8)));
typedef _Float16 half4_t __attribute__((ext_vector_type(4)));
typedef float f32x4 __attribute__((ext_vector_type(4)));

#define ROWS 131072   // B*S
#define BM   64       // rows per block
#define NBLK 2048     // ROWS / BM

// exact-erf GELU via Abramowitz-Stegun 7.1.26 (|err| <= 1.5e-7)
__device__ __forceinline__ float gelu_erf(float y) {
  float x  = y * 0.70710678118654752440f;
  float ax = fabsf(x);
  float t  = 1.0f / (1.0f + 0.3275911f * ax);
  float poly = ((((1.061405429f * t - 1.453152027f) * t + 1.421413741f) * t
                 - 0.284496736f) * t + 0.254829592f) * t;
  float e = __expf(-ax * ax);
  float erfv = copysignf(1.0f - poly * e, x);
  return 0.5f * y * (1.0f + erfv);
}

// ---------------- Kernel 1: W fp32 -> fp16 (one-off, ~0.5 MB) ----------------
__global__ __launch_bounds__(256) void wconv_kernel(
    const float4* __restrict__ W, half4_t* __restrict__ Wh)
{
  int i = blockIdx.x * 256 + threadIdx.x;
  float4 f = W[i];
  half4_t h;
  h[0] = (_Float16)f.x; h[1] = (_Float16)f.y;
  h[2] = (_Float16)f.z; h[3] = (_Float16)f.w;
  Wh[i] = h;
}

// ---- Kernel 2: FULLY FUSED, zero-redistribution -----------------------------
// Each thread loads exactly the x-elements its MFMA A-fragments need
// (rows wm*32+i*16+(lane&15), k = ks*32+(lane>>4)*8+{0..7}), accumulates
// LN stats in fp32, reduces across the 4-lane row-group via shfl_xor(16,32),
// and builds fp16 A-fragments in registers. No LDS, no scratch, no barriers.
// B direct from L2-resident Wh; bias+exact-GELU epilogue (R4-verified).
__global__ __launch_bounds__(256) void fused_kernel(
    const float* __restrict__ xa, const float* __restrict__ xb,
    const float* __restrict__ gamma, const float* __restrict__ beta,
    const _Float16* __restrict__ Wh, const float* __restrict__ bias,
    float* __restrict__ out)
{
  const int lane = threadIdx.x & 63;
  const int wave = threadIdx.x >> 6;
  const int wm = wave >> 1, wn = wave & 1;
  const size_t m0 = (size_t)blockIdx.x * BM;
  const int h = lane >> 4;           // k-chunk selector within 32-wide k-step

  // ---- Phase A: load own fragments' x-elements, v=a+b (fp16), fp32 stats ----
  half8 vf[2][8];
  float s[2], s2[2];
#pragma unroll
  for (int i = 0; i < 2; ++i) {
    const size_t row = m0 + (size_t)(wm * 32 + i * 16 + (lane & 15));
    const float4* pa = (const float4*)(xa + row * 256);
    const float4* pb = (const float4*)(xb + row * 256);
    float si = 0.f, s2i = 0.f;
#pragma unroll
    for (int ks = 0; ks < 8; ++ks) {
      const int c4 = ks * 8 + h * 2;     // float4 index of k = ks*32 + h*8
      float4 a0 = pa[c4],     b0 = pb[c4];
      float4 a1 = pa[c4 + 1], b1 = pb[c4 + 1];
      float v0 = a0.x + b0.x, v1 = a0.y + b0.y, v2 = a0.z + b0.z, v3 = a0.w + b0.w;
      float v4 = a1.x + b1.x, v5 = a1.y + b1.y, v6 = a1.z + b1.z, v7 = a1.w + b1.w;
      si  += v0 + v1 + v2 + v3 + v4 + v5 + v6 + v7;
      s2i += v0*v0 + v1*v1 + v2*v2 + v3*v3 + v4*v4 + v5*v5 + v6*v6 + v7*v7;
      half8 hv;
      hv[0] = (_Float16)v0; hv[1] = (_Float16)v1; hv[2] = (_Float16)v2; hv[3] = (_Float16)v3;
      hv[4] = (_Float16)v4; hv[5] = (_Float16)v5; hv[6] = (_Float16)v6; hv[7] = (_Float16)v7;
      vf[i][ks] = hv;
    }
    s[i] = si; s2[i] = s2i;
  }
  // 4-lane row-group reduction (lanes l, l^16, l^32, l^48 share a row)
#pragma unroll
  for (int i = 0; i < 2; ++i) {
    s[i]  += __shfl_xor(s[i],  16, 64);  s[i]  += __shfl_xor(s[i],  32, 64);
    s2[i] += __shfl_xor(s2[i], 16, 64);  s2[i] += __shfl_xor(s2[i], 32, 64);
  }
  float mean[2], rs[2];
#pragma unroll
  for (int i = 0; i < 2; ++i) {
    mean[i] = s[i] * (1.0f / 256.0f);
    float var = s2[i] * (1.0f / 256.0f) - mean[i] * mean[i];
    rs[i] = rsqrtf(var + 1e-12f);
  }

  // ---- Phase B: in-register LN transform -> fp16 A-fragments ----------------
  half8 afr[2][8];
#pragma unroll
  for (int ks = 0; ks < 8; ++ks) {
    const int c4 = ks * 8 + h * 2;
    float4 g0 = ((const float4*)gamma)[c4], g1 = ((const float4*)gamma)[c4 + 1];
    float4 e0 = ((const float4*)beta)[c4],  e1 = ((const float4*)beta)[c4 + 1];
#pragma unroll
    for (int i = 0; i < 2; ++i) {
      half8 hv = vf[i][ks];
      half8 r;
      r[0] = (_Float16)(((float)hv[0] - mean[i]) * rs[i] * g0.x + e0.x);
      r[1] = (_Float16)(((float)hv[1] - mean[i]) * rs[i] * g0.y + e0.y);
      r[2] = (_Float16)(((float)hv[2] - mean[i]) * rs[i] * g0.z + e0.z);
      r[3] = (_Float16)(((float)hv[3] - mean[i]) * rs[i] * g0.w + e0.w);
      r[4] = (_Float16)(((float)hv[4] - mean[i]) * rs[i] * g1.x + e1.x);
      r[5] = (_Float16)(((float)hv[5] - mean[i]) * rs[i] * g1.y + e1.y);
      r[6] = (_Float16)(((float)hv[6] - mean[i]) * rs[i] * g1.z + e1.z);
      r[7] = (_Float16)(((float)hv[7] - mean[i]) * rs[i] * g1.w + e1.w);
      afr[i][ks] = r;
    }
  }

  const int r0 = (lane >> 4) * 4;
  const int cc = lane & 15;

  // ---- Phase C: 8 n-chunks of 128 cols, B from global (L2-hot), R4-verified -
#pragma unroll 1
  for (int nt = 0; nt < 8; ++nt) {
    const int n0 = nt * 128;
    f32x4 acc[2][4] = {};
#pragma unroll
    for (int ks = 0; ks < 8; ++ks) {
      half8 bf[4];
#pragma unroll
      for (int j = 0; j < 4; ++j) {
        const int col = n0 + wn * 64 + j * 16 + (lane & 15);
        bf[j] = *(const half8*)(Wh + (size_t)col * 256 + ks * 32 + (lane >> 4) * 8);
      }
#pragma unroll
      for (int i = 0; i < 2; ++i)
#pragma unroll
        for (int j = 0; j < 4; ++j)
          acc[i][j] = __builtin_amdgcn_mfma_f32_16x16x32_f16(afr[i][ks], bf[j], acc[i][j], 0, 0, 0);
    }
    // fused epilogue: bias + exact GELU, fp32 store
#pragma unroll
    for (int j = 0; j < 4; ++j) {
      const int col = n0 + wn * 64 + j * 16 + cc;
      const float bv = bias[col];
#pragma unroll
      for (int i = 0; i < 2; ++i) {
        const size_t row = m0 + (size_t)(wm * 32 + i * 16 + r0);
        float* op = out + row * 1024 + col;
#pragma unroll
        for (int r = 0; r < 4; ++r)
          op[(size_t)r * 1024] = gelu_erf(acc[i][j][r] + bv);
      }
    }
  }
}

extern "C" void kernel_launch(void* const* d_in, const int* in_sizes, int n_in,
                              void* d_out, int out_size, void* d_ws, size_t ws_size,
                              hipStream_t stream) {
  const float* x399  = (const float*)d_in[0];
  const float* x365  = (const float*)d_in[1];
  const float* gamma = (const float*)d_in[2];
  const float* beta  = (const float*)d_in[3];
  const float* W     = (const float*)d_in[4];
  const float* bias  = (const float*)d_in[5];
  float* out = (float*)d_out;

  _Float16* Wh = (_Float16*)d_ws;   // 512 KiB

  wconv_kernel<<<256, 256, 0, stream>>>((const float4*)W, (half4_t*)Wh);
  fused_kernel<<<NBLK, 256, 0, stream>>>(
      x399, x365, gamma, beta, Wh, bias, out);
}